// Round 3
// baseline (1421.482 us; speedup 1.0000x reference)
//
#include <hip/hip_runtime.h>

#define NN 64
#define NI 6
#define TT 1024
#define BB 1024
#define TB (TT * BB)
#define NSCALE 0.13416407864998738f        // sqrt(2/alpha) * sigma
#define ARNSCALE 0.013416407864998739f     // alpha * NSCALE

__device__ __forceinline__ float rdlane(float v, int l) {
    return __int_as_float(__builtin_amdgcn_readlane(__float_as_int(v), l));
}

// Kernel 1: the recurrence. 1024 blocks x 64 threads; block = batch, lane = neuron.
// No LDS, no barriers, no shuffles -> nothing ever drains vmcnt/lgkmcnt on the
// critical path. Weights live per-lane; cross-neuron exchange via readlane (SALU
// broadcast operands). All hot-loop addressing is 32-bit int offsets.
__global__ __launch_bounds__(64) void latent_rnn(
    const float* __restrict__ u,      // (6, T, B)
    const float* __restrict__ rn,     // (64, T, B)
    const float* __restrict__ inn,    // (6, T, B)
    const float* __restrict__ Winp,   // (64, 6)
    const float* __restrict__ Wrec,   // (64, 64)
    float* __restrict__ states)       // (64, T, B)
{
    // XCD swizzle: 1024 blocks, 128 consecutive batches per XCD (1024%8==0, bijective)
    const int hw = blockIdx.x;
    const int b  = (hw & 7) * 128 + (hw >> 3);
    const int n  = threadIdx.x;       // lane = neuron

    // ---- per-lane weights ----
    float wr[NN];
#pragma unroll
    for (int k = 0; k < NN; k += 4) {
        float4 w4 = *reinterpret_cast<const float4*>(Wrec + n * NN + k);
        wr[k] = w4.x; wr[k + 1] = w4.y; wr[k + 2] = w4.z; wr[k + 3] = w4.w;
    }
    float wiu[NI], win[NI];
#pragma unroll
    for (int i = 0; i < NI; ++i) {
        wiu[i] = Winp[n * NI + i];
        win[i] = NSCALE * wiu[i];
    }

    // gather sources: lanes 0-5 -> u rows, 6-11 -> inn rows, 12+ alias lane n%12
    const int m = n % 12;
    const float* gsrc = (m < NI) ? (u + m * TB + b) : (inn + (m - NI) * TB + b);
    const float* rsrc = rn + n * TB + b;
    float* sdst = states + n * TB + b;

    sdst[0] = 0.0f;  // t = 0 state row is zero

    // ---- prefetch depth 4, static slots ----
    float rnb[4], gbf[4];
#pragma unroll
    for (int d = 0; d < 4; ++d) {
        rnb[d] = rsrc[d * BB];
        gbf[d] = gsrc[d * BB];
    }

    float x = 0.0f;

#define STEP(tcur, slot)                                                      \
    do {                                                                      \
        const float rcur = rnb[slot];                                         \
        const float gcur = gbf[slot];                                         \
        const int tp = ((tcur) + 4 < TT - 1) ? (tcur) + 4 : TT - 1;           \
        rnb[slot] = rsrc[tp * BB];                                            \
        gbf[slot] = gsrc[tp * BB];                                            \
        float a0 = 0.f, a1 = 0.f, a2 = 0.f, a3 = 0.f;                         \
        _Pragma("unroll")                                                     \
        for (int i = 0; i < NI; ++i) {                                        \
            a0 = fmaf(rdlane(gcur, i),      wiu[i], a0);                      \
            a1 = fmaf(rdlane(gcur, NI + i), win[i], a1);                      \
        }                                                                     \
        _Pragma("unroll")                                                     \
        for (int k = 0; k < NN; k += 4) {                                     \
            a0 = fmaf(rdlane(x, k + 0), wr[k + 0], a0);                       \
            a1 = fmaf(rdlane(x, k + 1), wr[k + 1], a1);                       \
            a2 = fmaf(rdlane(x, k + 2), wr[k + 2], a2);                       \
            a3 = fmaf(rdlane(x, k + 3), wr[k + 3], a3);                       \
        }                                                                     \
        const float pre = (a0 + a1) + (a2 + a3);                              \
        const float act = fmaxf(pre, 0.0f);                                   \
        x = fmaf(0.9f, x, fmaf(0.1f, act, ARNSCALE * rcur));                  \
        sdst[((tcur) + 1) * BB] = x;                                          \
    } while (0)

#pragma unroll 1
    for (int t = 0; t < 1020; t += 4) {
        STEP(t + 0, 0);
        STEP(t + 1, 1);
        STEP(t + 2, 2);
        STEP(t + 3, 3);
    }
    STEP(1020, 0);
    STEP(1021, 1);
    STEP(1022, 2);
#undef STEP
}

// Kernel 2: outputs = states @ Wout^T. Pure streaming (268 MB read, 8 MB write).
// Thread handles 4 consecutive (t,b) flat indices via float4; lanes contiguous.
__global__ __launch_bounds__(256) void out_proj(
    const float* __restrict__ states,   // (64, T*B)
    const float* __restrict__ Wout,     // (2, 64)
    float* __restrict__ outputs)        // (2, T*B)
{
    const int g4 = (blockIdx.x * 256 + threadIdx.x) * 4;  // flat t*B+b, x4
    float4 a0 = {0.f, 0.f, 0.f, 0.f};
    float4 a1 = {0.f, 0.f, 0.f, 0.f};
#pragma unroll
    for (int k = 0; k < NN; ++k) {
        const float4 s = *reinterpret_cast<const float4*>(states + k * TB + g4);
        const float w0 = Wout[k];
        const float w1 = Wout[NN + k];
        a0.x = fmaf(s.x, w0, a0.x); a0.y = fmaf(s.y, w0, a0.y);
        a0.z = fmaf(s.z, w0, a0.z); a0.w = fmaf(s.w, w0, a0.w);
        a1.x = fmaf(s.x, w1, a1.x); a1.y = fmaf(s.y, w1, a1.y);
        a1.z = fmaf(s.z, w1, a1.z); a1.w = fmaf(s.w, w1, a1.w);
    }
    *reinterpret_cast<float4*>(outputs + g4)      = a0;
    *reinterpret_cast<float4*>(outputs + TB + g4) = a1;
}

extern "C" void kernel_launch(void* const* d_in, const int* in_sizes, int n_in,
                              void* d_out, int out_size, void* d_ws, size_t ws_size,
                              hipStream_t stream) {
    const float* u    = (const float*)d_in[0];
    const float* rn   = (const float*)d_in[1];
    const float* inn  = (const float*)d_in[2];
    const float* Winp = (const float*)d_in[3];
    const float* Wrec = (const float*)d_in[4];
    const float* Wout = (const float*)d_in[5];

    float* states  = (float*)d_out;                          // 64*1024*1024
    float* outputs = (float*)d_out + (size_t)NN * TT * BB;   // 2*1024*1024

    latent_rnn<<<1024, 64, 0, stream>>>(u, rn, inn, Winp, Wrec, states);
    out_proj<<<1024, 256, 0, stream>>>(states, Wout, outputs);
}